// Round 5
// baseline (248.741 us; speedup 1.0000x reference)
//
#include <hip/hip_runtime.h>
#include <math.h>

#define B 8
#define C 256
#define L 2046
#define LP 2048
#define IC 64
#define OC 128
#define BN_EPS 1e-5f
#define INVN (1.f / 16384.f)   // 1/(B*LP)

// ws offsets (float units)
#define OFF_Y1T    0u          // conv1 out (pre-BN) bf16 [b][l][64]
#define OFF_Y2C    524288u     // conv1 out (pre-BN) bf16 [b][64][l]
#define OFF_Y51T   2097152u    // conv3 out (pre-BN) bf16 [b][l][64]
#define OFF_Y52T   2621440u
#define OFF_VB     3145728u    // v bf16 [b][64][l]
#define OFF_QT     3670016u    // q bf16 [b][l][8]
#define OFF_KT     3735552u
#define OFF_EPART  3866624u    // CAM gram partials [b][16][64][64]
#define OFF_STATS1 4423680u    // [4 copies][128ch][2] atomic sum/sumsq
#define OFF_STATS2 4424704u
#define OFF_W5BF   4425728u    // bf16 [128][256]
#define OFF_W67    4442112u    // bf16 [2][128][64]
#define OFF_WT     4450304u    // bf16 [2][3][64][64]
#define OFF_WQKV   4462592u    // bf16 [80][64]
#define OFF_BQKV   4465152u    // fp32 [80]

typedef __attribute__((ext_vector_type(8))) short bshort8;
typedef __attribute__((ext_vector_type(4))) float f32x4;

// fast bf16 round-half-up (differs from RTNE only on exact ties)
__device__ __forceinline__ unsigned short f2bf(float f) {
    union { float f; unsigned int u; } v; v.f = f;
    return (unsigned short)((v.u + 0x8000u) >> 16);
}
__device__ __forceinline__ float bf2f(unsigned short u) {
    union { unsigned int i; float f; } v; v.i = ((unsigned int)u) << 16;
    return v.f;
}
__device__ __forceinline__ unsigned int pk2(float a, float b) {
    union { float f; unsigned int u; } va, vb; va.f = a; vb.f = b;
    return __builtin_amdgcn_perm(vb.u + 0x8000u, va.u + 0x8000u, 0x07060302u);
}

// BN affine coefs from 4-copy atomic stats (t = caller-local thread id)
__device__ __forceinline__ void load_coef(const float* __restrict__ STATS,
        const float* __restrict__ g, const float* __restrict__ beta,
        int base, int cnt, float* cA, float* cB, int t) {
    if (t < cnt) {
        int ch = base + t;
        float s = STATS[ch * 2] + STATS[256 + ch * 2] + STATS[512 + ch * 2] + STATS[768 + ch * 2];
        float q = STATS[ch * 2 + 1] + STATS[256 + ch * 2 + 1] + STATS[512 + ch * 2 + 1] + STATS[768 + ch * 2 + 1];
        float mu = s * INVN;
        float var = q * INVN - mu * mu;
        float A = g[t] * rsqrtf(var + BN_EPS);
        cA[t] = A;
        cB[t] = beta[t] - mu * A;
    }
}

// ---- weight prep + stats zero + out b8-init ----
__global__ __launch_bounds__(256) void k_wprep(
        const float* __restrict__ W5a, const float* __restrict__ W5c,
        const float* __restrict__ W6, const float* __restrict__ W7,
        const float* __restrict__ W51, const float* __restrict__ W52,
        const float* __restrict__ Wq, const float* __restrict__ Wk,
        const float* __restrict__ Wv, const float* __restrict__ bq,
        const float* __restrict__ bk, const float* __restrict__ bv,
        const float* __restrict__ b8,
        unsigned short* __restrict__ W5BF, unsigned short* __restrict__ W67,
        unsigned short* __restrict__ WT, unsigned short* __restrict__ WQKV,
        float* __restrict__ BQKV, float* __restrict__ STATS1,
        float* __restrict__ STATS2, float* __restrict__ out_sasc) {
    int i = blockIdx.x * 256 + threadIdx.x;
    if (i < 32768) {
        int o = i >> 8, c = i & 255;
        W5BF[i] = f2bf(o < 64 ? W5a[o * 256 + c] : W5c[(o - 64) * 256 + c]);
    } else if (i < 49152) {
        int j = i - 32768; int g = j >> 13; int r = j & 8191;
        W67[j] = f2bf(g ? W7[r] : W6[r]);
    } else if (i < 73728) {
        int j = i - 49152;
        int c = j & 63, o = (j >> 6) & 63, wt = j >> 12; int w = wt / 3, t = wt % 3;
        const float* Ws = w ? W52 : W51;
        WT[j] = f2bf(Ws[(o * 64 + c) * 3 + t]);
    } else if (i < 78848) {
        int j = i - 73728; int o = j >> 6, c = j & 63;
        float v = o < 8 ? Wq[o * 64 + c] : (o < 16 ? Wk[(o - 8) * 64 + c] : Wv[(o - 16) * 64 + c]);
        WQKV[j] = f2bf(v);
    } else if (i < 78928) {
        int o = i - 78848;
        BQKV[o] = o < 8 ? bq[o] : (o < 16 ? bk[o - 8] : bv[o - 16]);
    } else if (i < 80976) {
        int j = i - 78928;
        if (j < 1024) STATS1[j] = 0.f; else STATS2[j - 1024] = 0.f;
    } else if (i < 82000) {
        int j = i - 80976;
        out_sasc[j] = b8[j & 127];
    }
}

// ---- conv1x1(x): single coalesced x pass; pre-BN bf16 + atomic stats ----
__global__ __launch_bounds__(256) void k_conv1(const float* __restrict__ x,
        const unsigned short* __restrict__ W5BF,
        unsigned short* __restrict__ Y1T, unsigned short* __restrict__ Y2C,
        float* __restrict__ STATS1) {
    __shared__ unsigned short xt[64][264];
    __shared__ float lds_part[4][64];
    int lt = blockIdx.x, b = blockIdx.y;
    int l0 = lt * 64;
    int t = threadIdx.x;
    {   // stage: lane j = l offset (coalesced), cg = channel quarter; packed b128 writes
        int j = t & 63, cg = t >> 6;
        int ls = l0 - 1 + j;
        bool ok = (ls >= 0) && (ls < L);
        const float* xs = x + (size_t)(b * C + cg * 64) * L + ls;
        unsigned short* row = &xt[j][cg * 64];
#pragma unroll
        for (int c8 = 0; c8 < 8; ++c8) {
            unsigned int pk[4];
#pragma unroll
            for (int i = 0; i < 4; ++i) {
                float v0 = ok ? xs[(size_t)(c8 * 8 + 2 * i) * L] : 0.f;
                float v1 = ok ? xs[(size_t)(c8 * 8 + 2 * i + 1) * L] : 0.f;
                pk[i] = pk2(v0, v1);
            }
            *(uint4*)(row + c8 * 8) = *(const uint4*)pk;
        }
    }
    __syncthreads();
    int w = t >> 6, lane = t & 63, n = lane & 15, quad = lane >> 4;
    bshort8 wf[2][8];
#pragma unroll
    for (int oi = 0; oi < 2; ++oi)
#pragma unroll
        for (int kt = 0; kt < 8; ++kt)
            wf[oi][kt] = *(const bshort8*)(W5BF + (size_t)((w * 2 + oi) * 16 + n) * C + kt * 32 + quad * 8);
    f32x4 acc[2][4];
#pragma unroll
    for (int oi = 0; oi < 2; ++oi)
#pragma unroll
        for (int sub = 0; sub < 4; ++sub) acc[oi][sub] = (f32x4){0.f, 0.f, 0.f, 0.f};
#pragma unroll
    for (int sub = 0; sub < 4; ++sub) {
        int lloc = sub * 16 + n;
#pragma unroll
        for (int kt = 0; kt < 8; ++kt) {
            bshort8 xb = *(const bshort8*)(&xt[lloc][kt * 32 + quad * 8]);
            acc[0][sub] = __builtin_amdgcn_mfma_f32_16x16x32_bf16(wf[0][kt], xb, acc[0][sub], 0, 0, 0);
            acc[1][sub] = __builtin_amdgcn_mfma_f32_16x16x32_bf16(wf[1][kt], xb, acc[1][sub], 0, 0, 0);
        }
    }
    if (w < 2) {
#pragma unroll
        for (int sub = 0; sub < 4; ++sub) {
            int lp = l0 + sub * 16 + n;
#pragma unroll
            for (int oi = 0; oi < 2; ++oi) {
                int ot = w * 2 + oi;
                uint2 pv;
                pv.x = pk2(acc[oi][sub][0], acc[oi][sub][1]);
                pv.y = pk2(acc[oi][sub][2], acc[oi][sub][3]);
                *(uint2*)(Y1T + ((size_t)(b * LP + lp)) * IC + ot * 16 + quad * 4) = pv;
            }
        }
    } else {
#pragma unroll
        for (int oi = 0; oi < 2; ++oi) {
            int ot = (w - 2) * 2 + oi;
#pragma unroll
            for (int r = 0; r < 4; ++r) {
                int o = ot * 16 + quad * 4 + r;
                unsigned short* dst = Y2C + ((size_t)(b * IC + o)) * LP + l0;
#pragma unroll
                for (int sub = 0; sub < 4; ++sub)
                    dst[sub * 16 + n] = f2bf(acc[oi][sub][r]);
            }
        }
    }
#pragma unroll
    for (int oi = 0; oi < 2; ++oi)
#pragma unroll
        for (int r = 0; r < 4; ++r) {
            float s = 0.f, q = 0.f;
#pragma unroll
            for (int sub = 0; sub < 4; ++sub) {
                float v = acc[oi][sub][r];
                s += v; q += v * v;
            }
#pragma unroll
            for (int msk = 1; msk < 16; msk <<= 1) {
                s += __shfl_xor(s, msk, 64);
                q += __shfl_xor(q, msk, 64);
            }
            if (n == 0) {
                int ci = oi * 16 + quad * 4 + r;
                lds_part[w][ci * 2] = s;
                lds_part[w][ci * 2 + 1] = q;
            }
        }
    __syncthreads();
    {
        int ch = t >> 1, wsrc = ch >> 5;
        int idx = ((ch & 31) << 1) | (t & 1);
        atomicAdd(&STATS1[(blockIdx.x & 3) * 256 + t], lds_part[wsrc][idx]);
    }
}

// ================= fuse1: qkv (256 blocks) | gram (32 blocks) =================
__device__ void role_qkv(char* dynsm, int lt, int b,
        const unsigned short* __restrict__ Y1T, const float* __restrict__ STATS1,
        const float* __restrict__ g5a, const float* __restrict__ b5a,
        const unsigned short* __restrict__ WQKV, const float* __restrict__ BQKV,
        unsigned short* __restrict__ QT, unsigned short* __restrict__ KT,
        unsigned short* __restrict__ VB) {
    float* cA = (float*)dynsm;
    float* cB = cA + 64;
    load_coef(STATS1, g5a, b5a, 0, 64, cA, cB, threadIdx.x);
    __syncthreads();
    int t = threadIdx.x;
    int w = t >> 6, lane = t & 63, n = lane & 15, quad = lane >> 4;
    int lrow = lt * 64 + w * 16 + n;
    bshort8 fb[2];
#pragma unroll
    for (int kt = 0; kt < 2; ++kt) {
        bshort8 raw = *(const bshort8*)(Y1T + ((size_t)(b * LP + lrow)) * IC + kt * 32 + quad * 8);
        bshort8 f;
#pragma unroll
        for (int j = 0; j < 8; ++j) {
            int c = kt * 32 + quad * 8 + j;
            float v = fmaxf(fmaf(cA[c], bf2f((unsigned short)raw[j]), cB[c]), 0.f);
            ((unsigned short*)&f)[j] = f2bf(v);
        }
        fb[kt] = f;
    }
    f32x4 acc[5];
#pragma unroll
    for (int ot = 0; ot < 5; ++ot) {
        f32x4 a = {0.f, 0.f, 0.f, 0.f};
#pragma unroll
        for (int kt = 0; kt < 2; ++kt) {
            bshort8 wf = *(const bshort8*)(WQKV + (size_t)(ot * 16 + n) * IC + kt * 32 + quad * 8);
            a = __builtin_amdgcn_mfma_f32_16x16x32_bf16(wf, fb[kt], a, 0, 0, 0);
        }
        acc[ot] = a;
    }
#pragma unroll
    for (int ot = 0; ot < 5; ++ot)
#pragma unroll
        for (int r = 0; r < 4; ++r) {
            int o = ot * 16 + quad * 4 + r;
            unsigned short bv16 = f2bf(acc[ot][r] + BQKV[o]);
            if (ot == 0) {
                if (o < 8) QT[((size_t)(b * LP + lrow)) * 8 + o] = bv16;
                else KT[((size_t)(b * LP + lrow)) * 8 + (o - 8)] = bv16;
            } else {
                VB[((size_t)(b * IC + (o - 16))) * LP + lrow] = bv16;
            }
        }
}

__device__ void role_gram(char* dynsm, int blk, int b,
        const unsigned short* __restrict__ Y2C, const float* __restrict__ STATS1,
        const float* __restrict__ g5c, const float* __restrict__ b5c,
        float* __restrict__ EPART) {
    float* cA = (float*)dynsm;
    float* cB = cA + 64;
    load_coef(STATS1, g5c, b5c, 64, 64, cA, cB, threadIdx.x);
    __syncthreads();
    int t = threadIdx.x;
    int w = t >> 6, lane = t & 63, n = lane & 15, quad = lane >> 4;
    f32x4 acc[4][4];
#pragma unroll
    for (int ti = 0; ti < 4; ++ti)
#pragma unroll
        for (int tj = 0; tj < 4; ++tj) acc[ti][tj] = (f32x4){0.f, 0.f, 0.f, 0.f};
    for (int chunk = 0; chunk < 4; ++chunk) {
        int lb = (blk * 4 + w) * 128 + chunk * 32 + quad * 8;
        bshort8 frag[4];
#pragma unroll
        for (int g = 0; g < 4; ++g) {
            int c = g * 16 + n;
            bshort8 raw = *(const bshort8*)(Y2C + ((size_t)(b * IC + c)) * LP + lb);
            bshort8 f;
            float A = cA[c], Bc = cB[c];
#pragma unroll
            for (int j = 0; j < 8; ++j)
                ((unsigned short*)&f)[j] = f2bf(fmaxf(fmaf(A, bf2f((unsigned short)raw[j]), Bc), 0.f));
            frag[g] = f;
        }
#pragma unroll
        for (int ti = 0; ti < 4; ++ti)
#pragma unroll
            for (int tj = 0; tj < 4; ++tj)
                acc[ti][tj] = __builtin_amdgcn_mfma_f32_16x16x32_bf16(frag[ti], frag[tj], acc[ti][tj], 0, 0, 0);
    }
    float* ep = EPART + ((size_t)(b * 16 + blk * 4 + w)) * 4096;
#pragma unroll
    for (int ti = 0; ti < 4; ++ti)
#pragma unroll
        for (int tj = 0; tj < 4; ++tj)
#pragma unroll
            for (int r = 0; r < 4; ++r)
                ep[(ti * 16 + quad * 4 + r) * 64 + tj * 16 + n] = acc[ti][tj][r];
}

__global__ __launch_bounds__(256) void k_fuse1(
        const unsigned short* __restrict__ Y1T, const unsigned short* __restrict__ Y2C,
        const float* __restrict__ STATS1,
        const float* __restrict__ g5a, const float* __restrict__ b5a,
        const float* __restrict__ g5c, const float* __restrict__ b5c,
        const unsigned short* __restrict__ WQKV, const float* __restrict__ BQKV,
        unsigned short* __restrict__ QT, unsigned short* __restrict__ KT,
        unsigned short* __restrict__ VB, float* __restrict__ EPART) {
    extern __shared__ char dynsm[];
    int idx = blockIdx.x;
    if (idx < 256) role_qkv(dynsm, idx & 31, idx >> 5, Y1T, STATS1, g5a, b5a,
                            WQKV, BQKV, QT, KT, VB);
    else { int g = idx - 256; role_gram(dynsm, g & 3, g >> 2, Y2C, STATS1, g5c, b5c, EPART); }
}

// ========== fuse2: merged attention + conv3, 512-thread blocks ==========
// PAM: 272 blocks (8 b x 34 tiles of 62 interior rows), 8 waves: wave w owns
//   Q-sub-tile (w&3) and key-half (w>>2) -> 16 barrier-free KV iters each,
//   V from L2-resident global. Halves combined in LDS (O0+O1, dn0+dn1),
//   then f1-add + conv3 (ot-tiles split across all 8 waves).
// CAM: 128 blocks; each 256-thread half runs one tile-job on its own LDS
//   slice (identical control flow keeps block barriers aligned).
// __launch_bounds__(512, 4): 4 waves/EU min -> VGPR cap 128 (vs default 64,
//   which serialized the 12 loads/iter and made each iter ~13k cycles).

// PAM LDS layout (bytes):
//   os      @0      : [2][64][65] f32 = 33280
//   ps|tile @33280  : 8x[16][72] bf16 = 18432 (tile [64][72]=9216 aliases)
//   cA      @51712  : 64 f32 ; cB @51968 ; dn @52224 [2][64] ; lds_part @52736 512f
// total 54784.  CAM half: 28448 x2 = 56896 -> dynamic request 56896.
#define CAM_HALF_BYTES 28448

__device__ void role_pam_full(char* dynsm, int qt, int b,
        const unsigned short* __restrict__ qT, const unsigned short* __restrict__ kT,
        const unsigned short* __restrict__ vb,
        const unsigned short* __restrict__ Y1T, const float* __restrict__ STATS1,
        const float* __restrict__ g5a, const float* __restrict__ b5a,
        const float* __restrict__ gamma, const unsigned short* __restrict__ WT,
        unsigned short* __restrict__ Y51T, float* __restrict__ STATS2) {
    float* os = (float*)dynsm;                             // [2][64][65] f32
    unsigned short* ps = (unsigned short*)(dynsm + 33280); // 8 x [16][72]
    unsigned short* tile = ps;                             // [64][72] epilogue alias
    float* cA = (float*)(dynsm + 51712);
    float* cB = cA + 64;
    float* dn = cB + 64;                                   // [2][64]
    float* lds_part = dn + 128;                            // 512 f32
    int base = qt * 62 - 1;                                // abs row of tile row 0
    int tid = threadIdx.x;
    int w8 = tid >> 6;              // 0..7
    int qsub = w8 & 3, kh = w8 >> 2;
    int lane = tid & 63, n = lane & 15, quad = lane >> 4;
    load_coef(STATS1, g5a, b5a, 0, 64, cA, cB, tid);
    int qrow = base + qsub * 16 + n;
    int qcl = qrow < 0 ? 0 : (qrow > LP - 1 ? LP - 1 : qrow);
    bshort8 qa = {};
    if (quad == 0)
        qa = *(const bshort8*)(qT + ((size_t)(b * LP + qcl)) * 8);
    f32x4 acc[4];
#pragma unroll
    for (int s = 0; s < 4; ++s) acc[s] = (f32x4){0.f, 0.f, 0.f, 0.f};
    float li[4] = {0.f, 0.f, 0.f, 0.f};
    unsigned short* pw = ps + w8 * 16 * 72;
    int mbase = kh * 1024;

    // K tile 0 preload (per-wave, no barrier)
    bshort8 kb[4];
#pragma unroll
    for (int s = 0; s < 4; ++s) kb[s] = (bshort8){};
    if (quad == 0) {
#pragma unroll
        for (int s = 0; s < 4; ++s)
            kb[s] = *(const bshort8*)(kT + ((size_t)(b * LP + mbase + s * 16 + n)) * 8);
    }
    // barrier-free KV sweep over this wave's key half (16 iters of 64)
    for (int it = 0; it < 16; ++it) {
        int m0 = mbase + it * 64;
        bshort8 vr[8];
#pragma unroll
        for (int step = 0; step < 2; ++step)
#pragma unroll
            for (int s = 0; s < 4; ++s)
                vr[step * 4 + s] = *(const bshort8*)(vb +
                    ((size_t)(b * IC + s * 16 + n)) * LP + m0 + step * 32 + quad * 8);
        bshort8 kn[4];
#pragma unroll
        for (int s = 0; s < 4; ++s) kn[s] = (bshort8){};
        if (it < 15 && quad == 0) {
            int m1 = m0 + 64;
#pragma unroll
            for (int s = 0; s < 4; ++s)
                kn[s] = *(const bshort8*)(kT + ((size_t)(b * LP + m1 + s * 16 + n)) * 8);
        }
        f32x4 sc[4];
#pragma unroll
        for (int s = 0; s < 4; ++s)
            sc[s] = __builtin_amdgcn_mfma_f32_16x16x32_bf16(qa, kb[s],
                        (f32x4){0.f, 0.f, 0.f, 0.f}, 0, 0, 0);
#pragma unroll
        for (int s = 0; s < 4; ++s)
#pragma unroll
            for (int r = 0; r < 4; ++r) {
                float p = __expf(sc[s][r]);
                li[r] += p;
                pw[(quad * 4 + r) * 72 + s * 16 + n] = f2bf(p);
            }
#pragma unroll
        for (int step = 0; step < 2; ++step) {
            bshort8 pa = *(const bshort8*)(pw + n * 72 + step * 32 + quad * 8);
#pragma unroll
            for (int s = 0; s < 4; ++s)
                acc[s] = __builtin_amdgcn_mfma_f32_16x16x32_bf16(pa, vr[step * 4 + s], acc[s], 0, 0, 0);
        }
#pragma unroll
        for (int s = 0; s < 4; ++s) kb[s] = kn[s];
    }
    // ---- partials to LDS: os[kh], dn[kh] ----
#pragma unroll
    for (int s = 0; s < 4; ++s)
#pragma unroll
        for (int r = 0; r < 4; ++r)
            os[kh * 4160 + (s * 16 + n) * 65 + qsub * 16 + quad * 4 + r] = acc[s][r];
#pragma unroll
    for (int r = 0; r < 4; ++r) {
        float s_ = li[r];
#pragma unroll
        for (int msk = 1; msk < 16; msk <<= 1) s_ += __shfl_xor(s_, msk, 64);
        if (n == 0) dn[kh * 64 + qsub * 16 + quad * 4 + r] = s_;
    }
    __syncthreads();
    float gm = gamma[0];
    {   // combine halves + normalize + f1-add; 512 threads: c=tid>>3, 8 rows each
        int c = tid >> 3, qc = tid & 7;
#pragma unroll
        for (int i = 0; i < 8; ++i) {
            int r = qc * 8 + i;
            int absr = base + r;
            float val = 0.f;
            if (absr >= 0 && absr < LP) {
                unsigned short raw = Y1T[((size_t)(b * LP + absr)) * IC + c];
                float f1v = fmaxf(fmaf(cA[c], bf2f(raw), cB[c]), 0.f);
                float o = os[c * 65 + r] + os[4160 + c * 65 + r];
                float d = dn[r] + dn[64 + r];
                val = fmaf(gm, o / d, f1v);
            }
            tile[r * 72 + c] = f2bf(val);   // zero == conv3 zero-pad at seq edges
        }
    }
    __syncthreads();
    {   // conv3: 8 waves = 4 row-groups x 2 ot-pairs. j=62,63 read tile rows
        // 64-65 (in-LDS garbage, masked by valid). 62 interior outputs.
        int wp = w8 & 3, og2 = w8 >> 2;
        int j = wp * 16 + n;
        int absout = base + 1 + j;
        bool valid = (j < 62) && (absout < LP);
        f32x4 a3[2];
#pragma unroll
        for (int oi = 0; oi < 2; ++oi) a3[oi] = (f32x4){0.f, 0.f, 0.f, 0.f};
#pragma unroll
        for (int t3 = 0; t3 < 3; ++t3) {
            bshort8 fb0 = *(const bshort8*)(tile + (j + t3) * 72 + quad * 8);
            bshort8 fb1 = *(const bshort8*)(tile + (j + t3) * 72 + 32 + quad * 8);
#pragma unroll
            for (int oi = 0; oi < 2; ++oi) {
                int ot = og2 * 2 + oi;
                bshort8 w0 = *(const bshort8*)(WT + ((size_t)(t3 * 64 + ot * 16 + n)) * IC + quad * 8);
                bshort8 w1 = *(const bshort8*)(WT + ((size_t)(t3 * 64 + ot * 16 + n)) * IC + 32 + quad * 8);
                a3[oi] = __builtin_amdgcn_mfma_f32_16x16x32_bf16(w0, fb0, a3[oi], 0, 0, 0);
                a3[oi] = __builtin_amdgcn_mfma_f32_16x16x32_bf16(w1, fb1, a3[oi], 0, 0, 0);
            }
        }
        if (valid) {
#pragma unroll
            for (int oi = 0; oi < 2; ++oi) {
                int ot = og2 * 2 + oi;
                uint2 pv;
                pv.x = pk2(a3[oi][0], a3[oi][1]);
                pv.y = pk2(a3[oi][2], a3[oi][3]);
                *(uint2*)(Y51T + ((size_t)(b * LP + absout)) * IC + ot * 16 + quad * 4) = pv;
            }
        }
#pragma unroll
        for (int oi = 0; oi < 2; ++oi)
#pragma unroll
            for (int r = 0; r < 4; ++r) {
                float s = valid ? a3[oi][r] : 0.f;
                float q = s * s;
#pragma unroll
                for (int msk = 1; msk < 16; msk <<= 1) {
                    s += __shfl_xor(s, msk, 64);
                    q += __shfl_xor(q, msk, 64);
                }
                if (n == 0) {
                    int cch = (og2 * 2 + oi) * 16 + quad * 4 + r;
                    lds_part[wp * 128 + cch * 2] = s;
                    lds_part[wp * 128 + cch * 2 + 1] = q;
                }
            }
        __syncthreads();
        if (tid < 128) {
            float s = lds_part[tid] + lds_part[128 + tid] + lds_part[256 + tid] + lds_part[384 + tid];
            atomicAdd(&STATS2[(qt & 3) * 256 + tid], s);
        }
    }
}

__device__ __forceinline__ void conv3_from_tile_cam(const unsigned short* tile,
        const unsigned short* __restrict__ WT, unsigned short* __restrict__ dst,
        int b, int l0, float* lds_part, float* __restrict__ STATS2,
        int blockx, int tl) {
    int w = tl >> 6, lane = tl & 63, n = lane & 15, quad = lane >> 4;
    int lrow = l0 + w * 16 + n;
    f32x4 acc[4];
#pragma unroll
    for (int ot = 0; ot < 4; ++ot) acc[ot] = (f32x4){0.f, 0.f, 0.f, 0.f};
#pragma unroll
    for (int t3 = 0; t3 < 3; ++t3) {
        int trow = w * 16 + n + t3;
        bshort8 fb0 = *(const bshort8*)(tile + trow * 72 + quad * 8);
        bshort8 fb1 = *(const bshort8*)(tile + trow * 72 + 32 + quad * 8);
#pragma unroll
        for (int ot = 0; ot < 4; ++ot) {
            bshort8 w0 = *(const bshort8*)(WT + ((size_t)(t3 * 64 + ot * 16 + n)) * IC + quad * 8);
            bshort8 w1 = *(const bshort8*)(WT + ((size_t)(t3 * 64 + ot * 16 + n)) * IC + 32 + quad * 8);
            acc[ot] = __builtin_amdgcn_mfma_f32_16x16x32_bf16(w0, fb0, acc[ot], 0, 0, 0);
            acc[ot] = __builtin_amdgcn_mfma_f32_16x16x32_bf16(w1, fb1, acc[ot], 0, 0, 0);
        }
    }
#pragma unroll
    for (int ot = 0; ot < 4; ++ot) {
        uint2 pv;
        pv.x = pk2(acc[ot][0], acc[ot][1]);
        pv.y = pk2(acc[ot][2], acc[ot][3]);
        *(uint2*)(dst + ((size_t)(b * LP + lrow)) * IC + ot * 16 + quad * 4) = pv;
    }
#pragma unroll
    for (int ot = 0; ot < 4; ++ot)
#pragma unroll
        for (int r = 0; r < 4; ++r) {
            float s = acc[ot][r], q = s * s;
#pragma unroll
            for (int msk = 1; msk < 16; msk <<= 1) {
                s += __shfl_xor(s, msk, 64);
                q += __shfl_xor(q, msk, 64);
            }
            if (n == 0) {
                int cch = ot * 16 + quad * 4 + r;
                lds_part[w * 128 + cch * 2] = s;
                lds_part[w * 128 + cch * 2 + 1] = q;
            }
        }
    __syncthreads();
    if (tl < 128) {
        float s = lds_part[tl] + lds_part[128 + tl] + lds_part[256 + tl] + lds_part[384 + tl];
        atomicAdd(&STATS2[(blockx & 3) * 256 + 128 + tl], s);
    }
}

__device__ void role_cam_full(char* sm, int tl, int lt, int b,
        const float* __restrict__ EPART, const unsigned short* __restrict__ Y2C,
        const float* __restrict__ STATS1,
        const float* __restrict__ g5c, const float* __restrict__ b5c,
        const float* __restrict__ gamma, const unsigned short* __restrict__ WT,
        unsigned short* __restrict__ Y52T, float* __restrict__ STATS2) {
    float* as = (float*)sm;                            // 4096 f32
    float* cA = as + 4096; float* cB = cA + 64;
    unsigned short* tile = (unsigned short*)(cB + 64); // [66][72]
    float* lds_part = (float*)(tile + 4752);           // 512 f32 (also fcol scratch)
    int l0 = lt * 64;
    load_coef(STATS1, g5c, b5c, 64, 64, cA, cB, tl);
    for (int idx = tl; idx < 4096; idx += 256) {       // sum gram partials (L2-resident)
        float s = 0.f;
#pragma unroll
        for (int ch = 0; ch < 16; ++ch) s += EPART[((size_t)(b * 16 + ch)) * 4096 + idx];
        as[idx] = s;
    }
    __syncthreads();
    {   // in-place softmax(min-shifted), 4 lanes per row
        int row = tl >> 2, qd = tl & 3;
        float v[16];
#pragma unroll
        for (int i = 0; i < 16; ++i) v[i] = as[row * 64 + qd * 16 + i];
        float mn = v[0];
#pragma unroll
        for (int i = 1; i < 16; ++i) mn = fminf(mn, v[i]);
        mn = fminf(mn, __shfl_xor(mn, 1, 64));
        mn = fminf(mn, __shfl_xor(mn, 2, 64));
        float s = 0.f;
#pragma unroll
        for (int i = 0; i < 16; ++i) { v[i] = __expf(mn - v[i]); s += v[i]; }
        s += __shfl_xor(s, 1, 64);
        s += __shfl_xor(s, 2, 64);
        float inv = 1.f / s;
#pragma unroll
        for (int i = 0; i < 16; ++i) as[row * 64 + qd * 16 + i] = v[i] * inv;
    }
    __syncthreads();
    float gm = gamma[0];
    {   // interior: lq row, cg = 16-channel group
        int lq = tl & 63, cg = tl >> 6;
        const unsigned short* fb = Y2C + (size_t)b * IC * LP + l0 + lq;
        float acc[16];
#pragma unroll
        for (int i = 0; i < 16; ++i) acc[i] = 0.f;
        for (int d4 = 0; d4 < 16; ++d4) {
            float fv[4];
#pragma unroll
            for (int i = 0; i < 4; ++i) {
                int d = 4 * d4 + i;
                fv[i] = fmaxf(fmaf(cA[d], bf2f(fb[(size_t)d * LP]), cB[d]), 0.f);
            }
#pragma unroll
            for (int cc = 0; cc < 16; ++cc) {
                const float4 a4 = *reinterpret_cast<const float4*>(as + (cg * 16 + cc) * 64 + d4 * 4);
                acc[cc] += a4.x * fv[0] + a4.y * fv[1] + a4.z * fv[2] + a4.w * fv[3];
            }
        }
#pragma unroll
        for (int cc = 0; cc < 16; ++cc) {
            int c = cg * 16 + cc;
            float res = fmaxf(fmaf(cA[c], bf2f(fb[(size_t)c * LP]), cB[c]), 0.f);
            tile[(1 + lq) * 72 + c] = f2bf(fmaf(gm, acc[cc], res));
        }
    }
    // halo: stage the two BN'd f-columns to LDS once
    float* fcol = lds_part;
    if (tl < 128) {
        int row = tl >> 6;
        int ch = tl & 63;
        int l = l0 - 1 + row * 65;
        float v = 0.f;
        if (l >= 0 && l < LP)
            v = fmaxf(fmaf(cA[ch], bf2f(Y2C[(size_t)b * IC * LP + (size_t)ch * LP + l]), cB[ch]), 0.f);
        fcol[row * 64 + ch] = v;
    }
    __syncthreads();
    if (tl < 128) {
        int sel = tl & 1;
        int row = sel ? 65 : 0;
        int ch = tl >> 1;
        int l = l0 - 1 + (sel ? 65 : 0);
        float val = 0.f;
        if (l >= 0 && l < LP) {
            const float* fc = fcol + sel * 64;
            float a = 0.f;
#pragma unroll 8
            for (int d = 0; d < 64; ++d) a = fmaf(as[ch * 64 + d], fc[d], a);
            val = fmaf(gm, a, fc[ch]);
        }
        tile[row * 72 + ch] = f2bf(val);
    }
    __syncthreads();
    conv3_from_tile_cam(tile, WT, Y52T, b, l0, lds_part, STATS2, lt, tl);
}

__global__ __launch_bounds__(512, 4) void k_fuse2(
        const unsigned short* __restrict__ QT, const unsigned short* __restrict__ KT,
        const unsigned short* __restrict__ VB,
        const unsigned short* __restrict__ Y1T, const unsigned short* __restrict__ Y2C,
        const float* __restrict__ STATS1,
        const float* __restrict__ g5a, const float* __restrict__ b5a,
        const float* __restrict__ g5c, const float* __restrict__ b5c,
        const float* __restrict__ gpam, const float* __restrict__ gcam,
        const float* __restrict__ EPART, const unsigned short* __restrict__ WTall,
        unsigned short* __restrict__ Y51T, unsigned short* __restrict__ Y52T,
        float* __restrict__ STATS2) {
    extern __shared__ char dynsm[];
    int idx = blockIdx.x;
    if (idx < 272) {
        int b = idx / 34; int qt = idx - b * 34;
        role_pam_full(dynsm, qt, b, QT, KT, VB, Y1T, STATS1, g5a, b5a, gpam,
                      WTall, Y51T, STATS2);
    } else {
        int g = idx - 272;                    // 0..127 -> jobs 2g, 2g+1
        int half = threadIdx.x >> 8;          // wave-uniform
        int j = g * 2 + half;                 // 0..255
        role_cam_full(dynsm + half * CAM_HALF_BYTES, threadIdx.x & 255,
                      j & 31, j >> 5, EPART, Y2C, STATS1, g5c, b5c, gcam,
                      WTall + 12288, Y52T, STATS2);
    }
}

// ---- final conv1x1 pair + fused sasc projection (out pre-initialized to b8) ----
__global__ __launch_bounds__(256) void k_final(const unsigned short* __restrict__ Y51T,
        const unsigned short* __restrict__ Y52T, const float* __restrict__ STATS2,
        const float* __restrict__ g51, const float* __restrict__ b51,
        const float* __restrict__ g52, const float* __restrict__ b52,
        const unsigned short* __restrict__ W67,
        const float* __restrict__ b6, const float* __restrict__ b7,
        const float* __restrict__ W8,
        float* __restrict__ out_sa, float* __restrict__ out_sc,
        float* __restrict__ out_sasc) {
    __shared__ float cA[128], cB[128];
    __shared__ float fsw[4][64];
    __shared__ float chsum[64];
    int lt = blockIdx.x, og = blockIdx.y, b = blockIdx.z;
    int t = threadIdx.x;
    if (t < 128) {
        float s = STATS2[t * 2] + STATS2[256 + t * 2] + STATS2[512 + t * 2] + STATS2[768 + t * 2];
        float q = STATS2[t * 2 + 1] + STATS2[256 + t * 2 + 1] + STATS2[512 + t * 2 + 1] + STATS2[768 + t * 2 + 1];
        float mu = s * INVN, var = q * INVN - mu * mu;
        float gv = t < 64 ? g51[t] : g52[t - 64];
        float bv = t < 64 ? b51[t] : b52[t - 64];
        float A = gv * rsqrtf(var + BN_EPS);
        cA[t] = A; cB[t] = bv - mu * A;
    }
    __syncthreads();
    int w = t >> 6, lane = t & 63, n = lane & 15, quad = lane >> 4;
    int lrow = lt * 64 + w * 16 + n;
    float fs_lane[16];
    bshort8 ba[2], bb[2];
#pragma unroll
    for (int kt = 0; kt < 2; ++kt) {
        bshort8 ra = *(const bshort8*)(Y51T + ((size_t)(b * LP + lrow)) * IC + kt * 32 + quad * 8);
        bshort8 rb = *(const bshort8*)(Y52T + ((size_t)(b * LP + lrow)) * IC + kt * 32 + quad * 8);
        bshort8 fa, fb;
#pragma unroll
        for (int j = 0; j < 8; ++j) {
            int c = kt * 32 + quad * 8 + j;
            float v1 = fmaxf(fmaf(cA[c], bf2f((unsigned short)ra[j]), cB[c]), 0.f);
            float v2 = fmaxf(fmaf(cA[64 + c], bf2f((unsigned short)rb[j]), cB[64 + c]), 0.f);
            ((unsigned short*)&fa)[j] = f2bf(v1);
            ((unsigned short*)&fb)[j] = f2bf(v2);
            fs_lane[kt * 8 + j] = v1 + v2;
        }
        ba[kt] = fa; bb[kt] = fb;
    }
    f32x4 accA[4], accB[4];
#pragma unroll
    for (int ot = 0; ot < 4; ++ot) {
        accA[ot] = (f32x4){0.f, 0.f, 0.f, 0.f};
        accB[ot] = (f32x4){0.f, 0.f, 0.f, 0.f};
    }
#pragma unroll
    for (int ot = 0; ot < 4; ++ot)
#pragma unroll
        for (int kt = 0; kt < 2; ++kt) {
            bshort8 wa = *(const bshort8*)(W67 + (size_t)(og * 64 + ot * 16 + n) * IC + kt * 32 + quad * 8);
            bshort8 wb = *(const bshort8*)(W67 + 8192 + (size_t)(og * 64 + ot * 16 + n) * IC + kt * 32 + quad * 8);
            accA[ot] = __builtin_amdgcn_mfma_f32_16x16x32_bf16(wa, ba[kt], accA[ot], 0, 0, 0);
            accB[ot] = __builtin_amdgcn_mfma_f32_16x16x32_bf16(wb, bb[kt], accB[ot], 0, 0, 0);
        }
#pragma unroll
    for (int ot = 0; ot < 4; ++ot)
#pragma unroll
        for (int r = 0; r < 4; ++r) {
            int o = og * 64 + ot * 16 + quad * 4 + r;
            out_sa[((size_t)(b * OC + o)) * LP + lrow] = accA[ot][r] + b6[o];
            out_sc[((size_t)(b * OC + o)) * LP + lrow] = accB[ot][r] + b7[o];
        }
    if (og == 0) {
#pragma unroll
        for (int i = 0; i < 16; ++i) {
            float s = fs_lane[i];
#pragma unroll
            for (int msk = 1; msk < 16; msk <<= 1) s += __shfl_xor(s, msk, 64);
            if (n == 0) {
                int c = (i >> 3) * 32 + quad * 8 + (i & 7);
                fsw[w][c] = s;
            }
        }
        __syncthreads();
        if (t < 64) chsum[t] = fsw[0][t] + fsw[1][t] + fsw[2][t] + fsw[3][t];
        __syncthreads();
        if (t < 128) {
            float s = 0.f;
            for (int c = 0; c < 64; ++c) s = fmaf(W8[t * 64 + c], chsum[c], s);
            atomicAdd(&out_sasc[b * OC + t], s * (1.f / (float)LP));
        }
    }
}

extern "C" void kernel_launch(void* const* d_in, const int* in_sizes, int n_in,
                              void* d_out, int out_size, void* d_ws, size_t ws_size,
                              hipStream_t stream) {
    (void)in_sizes; (void)n_in; (void)out_size; (void)ws_size;
    const float* x    = (const float*)d_in[0];
    const float* W5a  = (const float*)d_in[1];
    const float* g5a  = (const float*)d_in[2];
    const float* b5a  = (const float*)d_in[3];
    const float* W5c  = (const float*)d_in[4];
    const float* g5c  = (const float*)d_in[5];
    const float* b5c  = (const float*)d_in[6];
    const float* Wq   = (const float*)d_in[7];
    const float* bq   = (const float*)d_in[8];
    const float* Wk   = (const float*)d_in[9];
    const float* bk   = (const float*)d_in[10];
    const float* Wv   = (const float*)d_in[11];
    const float* bv   = (const float*)d_in[12];
    const float* gpam = (const float*)d_in[13];
    const float* gcam = (const float*)d_in[14];
    const float* W51  = (const float*)d_in[15];
    const float* g51  = (const float*)d_in[16];
    const float* b51  = (const float*)d_in[17];
    const float* W52  = (const float*)d_in[18];
    const float* g52  = (const float*)d_in[19];
    const float* b52  = (const float*)d_in[20];
    const float* W6   = (const float*)d_in[21];
    const float* b6   = (const float*)d_in[22];
    const float* W7   = (const float*)d_in[23];
    const float* b7   = (const float*)d_in[24];
    const float* W8   = (const float*)d_in[25];
    const float* b8   = (const float*)d_in[26];

    float* ws = (float*)d_ws;
    float* out = (float*)d_out;
    unsigned short* Y1T  = (unsigned short*)(ws + OFF_Y1T);
    unsigned short* Y2C  = (unsigned short*)(ws + OFF_Y2C);
    unsigned short* Y51T = (unsigned short*)(ws + OFF_Y51T);
    unsigned short* Y52T = (unsigned short*)(ws + OFF_Y52T);
    unsigned short* VB   = (unsigned short*)(ws + OFF_VB);
    unsigned short* QT   = (unsigned short*)(ws + OFF_QT);
    unsigned short* KT   = (unsigned short*)(ws + OFF_KT);
    float* EPART  = ws + OFF_EPART;
    float* STATS1 = ws + OFF_STATS1;
    float* STATS2 = ws + OFF_STATS2;
    unsigned short* W5BF = (unsigned short*)(ws + OFF_W5BF);
    unsigned short* W67  = (unsigned short*)(ws + OFF_W67);
    unsigned short* WT   = (unsigned short*)(ws + OFF_WT);
    unsigned short* WQKV = (unsigned short*)(ws + OFF_WQKV);
    float* BQKV = ws + OFF_BQKV;

    float* out_sa = out + B * OC;
    float* out_sc = out + B * OC + (size_t)B * OC * LP;

    k_wprep<<<321, 256, 0, stream>>>(W5a, W5c, W6, W7, W51, W52, Wq, Wk, Wv,
                                     bq, bk, bv, b8, W5BF, W67, WT, WQKV, BQKV,
                                     STATS1, STATS2, out);
    k_conv1<<<dim3(32, B), 256, 0, stream>>>(x, W5BF, Y1T, Y2C, STATS1);
    k_fuse1<<<288, 256, 512, stream>>>(Y1T, Y2C, STATS1, g5a, b5a, g5c, b5c,
                                       WQKV, BQKV, QT, KT, VB, EPART);
    k_fuse2<<<400, 512, 56896, stream>>>(QT, KT, VB, Y1T, Y2C, STATS1,
                                         g5a, b5a, g5c, b5c, gpam, gcam,
                                         EPART, WT, Y51T, Y52T, STATS2);
    k_final<<<dim3(32, 2, B), 256, 0, stream>>>(Y51T, Y52T, STATS2, g51, b51, g52, b52,
                                                W67, b6, b7, W8, out_sa, out_sc, out);
}

// Round 6
// 210.354 us; speedup vs baseline: 1.1825x; 1.1825x over previous
//
#include <hip/hip_runtime.h>
#include <math.h>

#define B 8
#define C 256
#define L 2046
#define LP 2048
#define IC 64
#define OC 128
#define BN_EPS 1e-5f
#define INVN (1.f / 16384.f)   // 1/(B*LP)

// ws offsets (float units)
#define OFF_Y1T    0u          // conv1 out (pre-BN) bf16 [b][l][64]
#define OFF_Y2C    524288u     // conv1 out (pre-BN) bf16 [b][64][l]
#define OFF_Y51T   2097152u    // conv3 out (pre-BN) bf16 [b][l][64]
#define OFF_Y52T   2621440u
#define OFF_VB     3145728u    // v bf16 [b][64][l]
#define OFF_QT     3670016u    // q bf16 [b][l][8]
#define OFF_KT     3735552u
#define OFF_EPART  3866624u    // CAM gram partials [b][16][64][64]
#define OFF_STATS1 4423680u    // [4 copies][128ch][2] atomic sum/sumsq
#define OFF_STATS2 4424704u
#define OFF_W5BF   4425728u    // bf16 [128][256]
#define OFF_W67    4442112u    // bf16 [2][128][64]
#define OFF_WT     4450304u    // bf16 [2][3][64][64]
#define OFF_WQKV   4462592u    // bf16 [80][64]
#define OFF_BQKV   4465152u    // fp32 [80]

typedef __attribute__((ext_vector_type(8))) short bshort8;
typedef __attribute__((ext_vector_type(4))) float f32x4;

// fast bf16 round-half-up (differs from RTNE only on exact ties)
__device__ __forceinline__ unsigned short f2bf(float f) {
    union { float f; unsigned int u; } v; v.f = f;
    return (unsigned short)((v.u + 0x8000u) >> 16);
}
__device__ __forceinline__ float bf2f(unsigned short u) {
    union { unsigned int i; float f; } v; v.i = ((unsigned int)u) << 16;
    return v.f;
}
__device__ __forceinline__ unsigned int pk2(float a, float b) {
    union { float f; unsigned int u; } va, vb; va.f = a; vb.f = b;
    return __builtin_amdgcn_perm(vb.u + 0x8000u, va.u + 0x8000u, 0x07060302u);
}

// BN affine coefs from 4-copy atomic stats (t = caller-local thread id)
__device__ __forceinline__ void load_coef(const float* __restrict__ STATS,
        const float* __restrict__ g, const float* __restrict__ beta,
        int base, int cnt, float* cA, float* cB, int t) {
    if (t < cnt) {
        int ch = base + t;
        float s = STATS[ch * 2] + STATS[256 + ch * 2] + STATS[512 + ch * 2] + STATS[768 + ch * 2];
        float q = STATS[ch * 2 + 1] + STATS[256 + ch * 2 + 1] + STATS[512 + ch * 2 + 1] + STATS[768 + ch * 2 + 1];
        float mu = s * INVN;
        float var = q * INVN - mu * mu;
        float A = g[t] * rsqrtf(var + BN_EPS);
        cA[t] = A;
        cB[t] = beta[t] - mu * A;
    }
}

// ---- weight prep + stats zero + out b8-init ----
__global__ __launch_bounds__(256) void k_wprep(
        const float* __restrict__ W5a, const float* __restrict__ W5c,
        const float* __restrict__ W6, const float* __restrict__ W7,
        const float* __restrict__ W51, const float* __restrict__ W52,
        const float* __restrict__ Wq, const float* __restrict__ Wk,
        const float* __restrict__ Wv, const float* __restrict__ bq,
        const float* __restrict__ bk, const float* __restrict__ bv,
        const float* __restrict__ b8,
        unsigned short* __restrict__ W5BF, unsigned short* __restrict__ W67,
        unsigned short* __restrict__ WT, unsigned short* __restrict__ WQKV,
        float* __restrict__ BQKV, float* __restrict__ STATS1,
        float* __restrict__ STATS2, float* __restrict__ out_sasc) {
    int i = blockIdx.x * 256 + threadIdx.x;
    if (i < 32768) {
        int o = i >> 8, c = i & 255;
        W5BF[i] = f2bf(o < 64 ? W5a[o * 256 + c] : W5c[(o - 64) * 256 + c]);
    } else if (i < 49152) {
        int j = i - 32768; int g = j >> 13; int r = j & 8191;
        W67[j] = f2bf(g ? W7[r] : W6[r]);
    } else if (i < 73728) {
        int j = i - 49152;
        int c = j & 63, o = (j >> 6) & 63, wt = j >> 12; int w = wt / 3, t = wt % 3;
        const float* Ws = w ? W52 : W51;
        WT[j] = f2bf(Ws[(o * 64 + c) * 3 + t]);
    } else if (i < 78848) {
        int j = i - 73728; int o = j >> 6, c = j & 63;
        float v = o < 8 ? Wq[o * 64 + c] : (o < 16 ? Wk[(o - 8) * 64 + c] : Wv[(o - 16) * 64 + c]);
        WQKV[j] = f2bf(v);
    } else if (i < 78928) {
        int o = i - 78848;
        BQKV[o] = o < 8 ? bq[o] : (o < 16 ? bk[o - 8] : bv[o - 16]);
    } else if (i < 80976) {
        int j = i - 78928;
        if (j < 1024) STATS1[j] = 0.f; else STATS2[j - 1024] = 0.f;
    } else if (i < 82000) {
        int j = i - 80976;
        out_sasc[j] = b8[j & 127];
    }
}

// ---- conv1x1(x): single coalesced x pass; pre-BN bf16 + atomic stats ----
__global__ __launch_bounds__(256) void k_conv1(const float* __restrict__ x,
        const unsigned short* __restrict__ W5BF,
        unsigned short* __restrict__ Y1T, unsigned short* __restrict__ Y2C,
        float* __restrict__ STATS1) {
    __shared__ unsigned short xt[64][264];
    __shared__ float lds_part[4][64];
    int lt = blockIdx.x, b = blockIdx.y;
    int l0 = lt * 64;
    int t = threadIdx.x;
    {   // stage: lane j = l offset (coalesced), cg = channel quarter; packed b128 writes
        int j = t & 63, cg = t >> 6;
        int ls = l0 - 1 + j;
        bool ok = (ls >= 0) && (ls < L);
        const float* xs = x + (size_t)(b * C + cg * 64) * L + ls;
        unsigned short* row = &xt[j][cg * 64];
#pragma unroll
        for (int c8 = 0; c8 < 8; ++c8) {
            unsigned int pk[4];
#pragma unroll
            for (int i = 0; i < 4; ++i) {
                float v0 = ok ? xs[(size_t)(c8 * 8 + 2 * i) * L] : 0.f;
                float v1 = ok ? xs[(size_t)(c8 * 8 + 2 * i + 1) * L] : 0.f;
                pk[i] = pk2(v0, v1);
            }
            *(uint4*)(row + c8 * 8) = *(const uint4*)pk;
        }
    }
    __syncthreads();
    int w = t >> 6, lane = t & 63, n = lane & 15, quad = lane >> 4;
    bshort8 wf[2][8];
#pragma unroll
    for (int oi = 0; oi < 2; ++oi)
#pragma unroll
        for (int kt = 0; kt < 8; ++kt)
            wf[oi][kt] = *(const bshort8*)(W5BF + (size_t)((w * 2 + oi) * 16 + n) * C + kt * 32 + quad * 8);
    f32x4 acc[2][4];
#pragma unroll
    for (int oi = 0; oi < 2; ++oi)
#pragma unroll
        for (int sub = 0; sub < 4; ++sub) acc[oi][sub] = (f32x4){0.f, 0.f, 0.f, 0.f};
#pragma unroll
    for (int sub = 0; sub < 4; ++sub) {
        int lloc = sub * 16 + n;
#pragma unroll
        for (int kt = 0; kt < 8; ++kt) {
            bshort8 xb = *(const bshort8*)(&xt[lloc][kt * 32 + quad * 8]);
            acc[0][sub] = __builtin_amdgcn_mfma_f32_16x16x32_bf16(wf[0][kt], xb, acc[0][sub], 0, 0, 0);
            acc[1][sub] = __builtin_amdgcn_mfma_f32_16x16x32_bf16(wf[1][kt], xb, acc[1][sub], 0, 0, 0);
        }
    }
    if (w < 2) {
#pragma unroll
        for (int sub = 0; sub < 4; ++sub) {
            int lp = l0 + sub * 16 + n;
#pragma unroll
            for (int oi = 0; oi < 2; ++oi) {
                int ot = w * 2 + oi;
                uint2 pv;
                pv.x = pk2(acc[oi][sub][0], acc[oi][sub][1]);
                pv.y = pk2(acc[oi][sub][2], acc[oi][sub][3]);
                *(uint2*)(Y1T + ((size_t)(b * LP + lp)) * IC + ot * 16 + quad * 4) = pv;
            }
        }
    } else {
#pragma unroll
        for (int oi = 0; oi < 2; ++oi) {
            int ot = (w - 2) * 2 + oi;
#pragma unroll
            for (int r = 0; r < 4; ++r) {
                int o = ot * 16 + quad * 4 + r;
                unsigned short* dst = Y2C + ((size_t)(b * IC + o)) * LP + l0;
#pragma unroll
                for (int sub = 0; sub < 4; ++sub)
                    dst[sub * 16 + n] = f2bf(acc[oi][sub][r]);
            }
        }
    }
#pragma unroll
    for (int oi = 0; oi < 2; ++oi)
#pragma unroll
        for (int r = 0; r < 4; ++r) {
            float s = 0.f, q = 0.f;
#pragma unroll
            for (int sub = 0; sub < 4; ++sub) {
                float v = acc[oi][sub][r];
                s += v; q += v * v;
            }
#pragma unroll
            for (int msk = 1; msk < 16; msk <<= 1) {
                s += __shfl_xor(s, msk, 64);
                q += __shfl_xor(q, msk, 64);
            }
            if (n == 0) {
                int ci = oi * 16 + quad * 4 + r;
                lds_part[w][ci * 2] = s;
                lds_part[w][ci * 2 + 1] = q;
            }
        }
    __syncthreads();
    {
        int ch = t >> 1, wsrc = ch >> 5;
        int idx = ((ch & 31) << 1) | (t & 1);
        atomicAdd(&STATS1[(blockIdx.x & 3) * 256 + t], lds_part[wsrc][idx]);
    }
}

// ================= fuse1: qkv (256 blocks) | gram (32 blocks) =================
__device__ void role_qkv(char* dynsm, int lt, int b,
        const unsigned short* __restrict__ Y1T, const float* __restrict__ STATS1,
        const float* __restrict__ g5a, const float* __restrict__ b5a,
        const unsigned short* __restrict__ WQKV, const float* __restrict__ BQKV,
        unsigned short* __restrict__ QT, unsigned short* __restrict__ KT,
        unsigned short* __restrict__ VB) {
    float* cA = (float*)dynsm;
    float* cB = cA + 64;
    load_coef(STATS1, g5a, b5a, 0, 64, cA, cB, threadIdx.x);
    __syncthreads();
    int t = threadIdx.x;
    int w = t >> 6, lane = t & 63, n = lane & 15, quad = lane >> 4;
    int lrow = lt * 64 + w * 16 + n;
    bshort8 fb[2];
#pragma unroll
    for (int kt = 0; kt < 2; ++kt) {
        bshort8 raw = *(const bshort8*)(Y1T + ((size_t)(b * LP + lrow)) * IC + kt * 32 + quad * 8);
        bshort8 f;
#pragma unroll
        for (int j = 0; j < 8; ++j) {
            int c = kt * 32 + quad * 8 + j;
            float v = fmaxf(fmaf(cA[c], bf2f((unsigned short)raw[j]), cB[c]), 0.f);
            ((unsigned short*)&f)[j] = f2bf(v);
        }
        fb[kt] = f;
    }
    f32x4 acc[5];
#pragma unroll
    for (int ot = 0; ot < 5; ++ot) {
        f32x4 a = {0.f, 0.f, 0.f, 0.f};
#pragma unroll
        for (int kt = 0; kt < 2; ++kt) {
            bshort8 wf = *(const bshort8*)(WQKV + (size_t)(ot * 16 + n) * IC + kt * 32 + quad * 8);
            a = __builtin_amdgcn_mfma_f32_16x16x32_bf16(wf, fb[kt], a, 0, 0, 0);
        }
        acc[ot] = a;
    }
#pragma unroll
    for (int ot = 0; ot < 5; ++ot)
#pragma unroll
        for (int r = 0; r < 4; ++r) {
            int o = ot * 16 + quad * 4 + r;
            unsigned short bv16 = f2bf(acc[ot][r] + BQKV[o]);
            if (ot == 0) {
                if (o < 8) QT[((size_t)(b * LP + lrow)) * 8 + o] = bv16;
                else KT[((size_t)(b * LP + lrow)) * 8 + (o - 8)] = bv16;
            } else {
                VB[((size_t)(b * IC + (o - 16))) * LP + lrow] = bv16;
            }
        }
}

__device__ void role_gram(char* dynsm, int blk, int b,
        const unsigned short* __restrict__ Y2C, const float* __restrict__ STATS1,
        const float* __restrict__ g5c, const float* __restrict__ b5c,
        float* __restrict__ EPART) {
    float* cA = (float*)dynsm;
    float* cB = cA + 64;
    load_coef(STATS1, g5c, b5c, 64, 64, cA, cB, threadIdx.x);
    __syncthreads();
    int t = threadIdx.x;
    int w = t >> 6, lane = t & 63, n = lane & 15, quad = lane >> 4;
    f32x4 acc[4][4];
#pragma unroll
    for (int ti = 0; ti < 4; ++ti)
#pragma unroll
        for (int tj = 0; tj < 4; ++tj) acc[ti][tj] = (f32x4){0.f, 0.f, 0.f, 0.f};
    for (int chunk = 0; chunk < 4; ++chunk) {
        int lb = (blk * 4 + w) * 128 + chunk * 32 + quad * 8;
        bshort8 frag[4];
#pragma unroll
        for (int g = 0; g < 4; ++g) {
            int c = g * 16 + n;
            bshort8 raw = *(const bshort8*)(Y2C + ((size_t)(b * IC + c)) * LP + lb);
            bshort8 f;
            float A = cA[c], Bc = cB[c];
#pragma unroll
            for (int j = 0; j < 8; ++j)
                ((unsigned short*)&f)[j] = f2bf(fmaxf(fmaf(A, bf2f((unsigned short)raw[j]), Bc), 0.f));
            frag[g] = f;
        }
#pragma unroll
        for (int ti = 0; ti < 4; ++ti)
#pragma unroll
            for (int tj = 0; tj < 4; ++tj)
                acc[ti][tj] = __builtin_amdgcn_mfma_f32_16x16x32_bf16(frag[ti], frag[tj], acc[ti][tj], 0, 0, 0);
    }
    float* ep = EPART + ((size_t)(b * 16 + blk * 4 + w)) * 4096;
#pragma unroll
    for (int ti = 0; ti < 4; ++ti)
#pragma unroll
        for (int tj = 0; tj < 4; ++tj)
#pragma unroll
            for (int r = 0; r < 4; ++r)
                ep[(ti * 16 + quad * 4 + r) * 64 + tj * 16 + n] = acc[ti][tj][r];
}

__global__ __launch_bounds__(256) void k_fuse1(
        const unsigned short* __restrict__ Y1T, const unsigned short* __restrict__ Y2C,
        const float* __restrict__ STATS1,
        const float* __restrict__ g5a, const float* __restrict__ b5a,
        const float* __restrict__ g5c, const float* __restrict__ b5c,
        const unsigned short* __restrict__ WQKV, const float* __restrict__ BQKV,
        unsigned short* __restrict__ QT, unsigned short* __restrict__ KT,
        unsigned short* __restrict__ VB, float* __restrict__ EPART) {
    extern __shared__ char dynsm[];
    int idx = blockIdx.x;
    if (idx < 256) role_qkv(dynsm, idx & 31, idx >> 5, Y1T, STATS1, g5a, b5a,
                            WQKV, BQKV, QT, KT, VB);
    else { int g = idx - 256; role_gram(dynsm, g & 3, g >> 2, Y2C, STATS1, g5c, b5c, EPART); }
}

// ========== fuse2: merged attention + conv3, 256-thread blocks ==========
// PAM: 272 blocks (8 b x 34 tiles of 62 interior rows), 4 waves = 4 q-subtiles.
//   Keys processed in 16 super-tiles of 128 keys, V double-buffered in LDS with
//   ONE barrier per super-tile (16 total). T14 split: next super's global loads
//   issue at super-top (sched_barrier-pinned), ds_write lands after the two
//   64-key inner bodies -> V latency hides under QK/exp/PV compute.
// CAM: 256 blocks, proven body (redundant softmax from EPART, then conv3).
//
// PAM LDS layout (bytes):
//   vs0 @0 (17408), vs1 @17408 (17408)   V super [64ch][136] bf16
//   ps  @34816 (9216)  4 x [16][72] P staging; tile [64][72] aliases
//   cA @44032 (256), cB @44288 (256), dn @44544 (256), lds_part @44800 (2048)
//   total 46848.  os [64][65] f32 (16640) aliases vs0 in epilogue.
//   CAM needs 28448 <= 46848.
__device__ void role_pam_full(char* dynsm, int qt, int b,
        const unsigned short* __restrict__ qT, const unsigned short* __restrict__ kT,
        const unsigned short* __restrict__ vb,
        const unsigned short* __restrict__ Y1T, const float* __restrict__ STATS1,
        const float* __restrict__ g5a, const float* __restrict__ b5a,
        const float* __restrict__ gamma, const unsigned short* __restrict__ WT,
        unsigned short* __restrict__ Y51T, float* __restrict__ STATS2) {
    unsigned short* vs0 = (unsigned short*)dynsm;          // [64][136]
    unsigned short* vs1 = vs0 + 8704;
    unsigned short* ps  = (unsigned short*)(dynsm + 34816);
    unsigned short* tile = ps;                             // [64][72] epilogue alias
    float* os = (float*)dynsm;                             // [64][65] epilogue alias
    float* cA = (float*)(dynsm + 44032);
    float* cB = cA + 64;
    float* dn = cB + 64;
    float* lds_part = dn + 64;                             // 512 f32
    int base = qt * 62 - 1;                                // abs row of tile row 0
    int tid = threadIdx.x;
    int wq = tid >> 6, lane = tid & 63, n = lane & 15, quad = lane >> 4;
    int sch = tid >> 2, skf = (tid & 3) * 32;              // stage: channel, key off
    load_coef(STATS1, g5a, b5a, 0, 64, cA, cB, tid);
    int qrow = base + wq * 16 + n;
    int qcl = qrow < 0 ? 0 : (qrow > LP - 1 ? LP - 1 : qrow);
    bshort8 qa = {};
    if (quad == 0)
        qa = *(const bshort8*)(qT + ((size_t)(b * LP + qcl)) * 8);
    f32x4 acc[4];
#pragma unroll
    for (int s = 0; s < 4; ++s) acc[s] = (f32x4){0.f, 0.f, 0.f, 0.f};
    float li[4] = {0.f, 0.f, 0.f, 0.f};
    unsigned short* pw = ps + wq * 16 * 72;
    const unsigned short* vsrc = vb + ((size_t)(b * IC + sch)) * LP + skf;

    {   // prologue: stage V super 0 (64B/thread, contiguous)
        bshort8 v0[4];
#pragma unroll
        for (int i = 0; i < 4; ++i) v0[i] = *(const bshort8*)(vsrc + i * 8);
        unsigned short* d = vs0 + sch * 136 + skf;
#pragma unroll
        for (int i = 0; i < 4; ++i) *(bshort8*)(d + i * 8) = v0[i];
    }
    // K tile 0 preload (per-wave, registers)
    bshort8 kb[4];
#pragma unroll
    for (int s = 0; s < 4; ++s) kb[s] = (bshort8){};
    if (quad == 0) {
#pragma unroll
        for (int s = 0; s < 4; ++s)
            kb[s] = *(const bshort8*)(kT + ((size_t)(b * LP + s * 16 + n)) * 8);
    }
    __syncthreads();
    for (int sup = 0; sup < 16; ++sup) {
        unsigned short* cur = (sup & 1) ? vs1 : vs0;
        unsigned short* nxt = (sup & 1) ? vs0 : vs1;
        bshort8 vrg[4];
        if (sup < 15) {   // T14 issue-early: loads for super sup+1
#pragma unroll
            for (int i = 0; i < 4; ++i)
                vrg[i] = *(const bshort8*)(vsrc + (sup + 1) * 128 + i * 8);
        }
        __builtin_amdgcn_sched_barrier(0);   // pin loads above the compute
#pragma unroll
        for (int ki = 0; ki < 2; ++ki) {
            int g = sup * 2 + ki;            // 64-key tile index 0..31
            bshort8 kn[4];
#pragma unroll
            for (int s = 0; s < 4; ++s) kn[s] = (bshort8){};
            if (g < 31 && quad == 0) {
#pragma unroll
                for (int s = 0; s < 4; ++s)
                    kn[s] = *(const bshort8*)(kT + ((size_t)(b * LP + (g + 1) * 64 + s * 16 + n)) * 8);
            }
            f32x4 sc[4];
#pragma unroll
            for (int s = 0; s < 4; ++s)
                sc[s] = __builtin_amdgcn_mfma_f32_16x16x32_bf16(qa, kb[s],
                            (f32x4){0.f, 0.f, 0.f, 0.f}, 0, 0, 0);
#pragma unroll
            for (int s = 0; s < 4; ++s)
#pragma unroll
                for (int r = 0; r < 4; ++r) {
                    float p = __expf(sc[s][r]);
                    li[r] += p;
                    pw[(quad * 4 + r) * 72 + s * 16 + n] = f2bf(p);
                }
#pragma unroll
            for (int step = 0; step < 2; ++step) {
                bshort8 pa = *(const bshort8*)(pw + n * 72 + step * 32 + quad * 8);
#pragma unroll
                for (int s = 0; s < 4; ++s) {
                    bshort8 vf = *(const bshort8*)(cur + (s * 16 + n) * 136 + ki * 64 + step * 32 + quad * 8);
                    acc[s] = __builtin_amdgcn_mfma_f32_16x16x32_bf16(pa, vf, acc[s], 0, 0, 0);
                }
            }
#pragma unroll
            for (int s = 0; s < 4; ++s) kb[s] = kn[s];
        }
        if (sup < 15) {   // T14 write-late: vmcnt wait lands here, post-compute
            unsigned short* d = nxt + sch * 136 + skf;
#pragma unroll
            for (int i = 0; i < 4; ++i) *(bshort8*)(d + i * 8) = vrg[i];
        }
        __syncthreads();  // one barrier per 128 keys (was per 64)
    }
    // ---- epilogue: O -> LDS, denominators, combine with f1, conv3 ----
#pragma unroll
    for (int s = 0; s < 4; ++s)
#pragma unroll
        for (int r = 0; r < 4; ++r)
            os[(s * 16 + n) * 65 + wq * 16 + quad * 4 + r] = acc[s][r];
#pragma unroll
    for (int r = 0; r < 4; ++r) {
        float s_ = li[r];
#pragma unroll
        for (int msk = 1; msk < 16; msk <<= 1) s_ += __shfl_xor(s_, msk, 64);
        if (n == 0) dn[wq * 16 + quad * 4 + r] = s_;
    }
    __syncthreads();
    float gm = gamma[0];
    {
        int c = tid >> 2, qc = tid & 3;
#pragma unroll
        for (int i = 0; i < 16; ++i) {
            int r = qc * 16 + i;
            int absr = base + r;
            float val = 0.f;
            if (absr >= 0 && absr < LP) {
                unsigned short raw = Y1T[((size_t)(b * LP + absr)) * IC + c];
                float f1v = fmaxf(fmaf(cA[c], bf2f(raw), cB[c]), 0.f);
                val = fmaf(gm, os[c * 65 + r] / dn[r], f1v);
            }
            tile[r * 72 + c] = f2bf(val);   // zero == conv3 zero-pad at seq edges
        }
    }
    __syncthreads();
    {   // conv3: 62 interior output rows (j=62,63 read tile rows 64-65 -> in-LDS
        // garbage; contained to their own masked output columns)
        int j = wq * 16 + n;
        int absout = base + 1 + j;
        bool valid = (j < 62) && (absout < LP);
        f32x4 a3[4];
#pragma unroll
        for (int ot = 0; ot < 4; ++ot) a3[ot] = (f32x4){0.f, 0.f, 0.f, 0.f};
#pragma unroll
        for (int t3 = 0; t3 < 3; ++t3) {
            bshort8 fb0 = *(const bshort8*)(tile + (j + t3) * 72 + quad * 8);
            bshort8 fb1 = *(const bshort8*)(tile + (j + t3) * 72 + 32 + quad * 8);
#pragma unroll
            for (int ot = 0; ot < 4; ++ot) {
                bshort8 w0 = *(const bshort8*)(WT + ((size_t)(t3 * 64 + ot * 16 + n)) * IC + quad * 8);
                bshort8 w1 = *(const bshort8*)(WT + ((size_t)(t3 * 64 + ot * 16 + n)) * IC + 32 + quad * 8);
                a3[ot] = __builtin_amdgcn_mfma_f32_16x16x32_bf16(w0, fb0, a3[ot], 0, 0, 0);
                a3[ot] = __builtin_amdgcn_mfma_f32_16x16x32_bf16(w1, fb1, a3[ot], 0, 0, 0);
            }
        }
        if (valid) {
#pragma unroll
            for (int ot = 0; ot < 4; ++ot) {
                uint2 pv;
                pv.x = pk2(a3[ot][0], a3[ot][1]);
                pv.y = pk2(a3[ot][2], a3[ot][3]);
                *(uint2*)(Y51T + ((size_t)(b * LP + absout)) * IC + ot * 16 + quad * 4) = pv;
            }
        }
#pragma unroll
        for (int ot = 0; ot < 4; ++ot)
#pragma unroll
            for (int r = 0; r < 4; ++r) {
                float s = valid ? a3[ot][r] : 0.f;
                float q = s * s;
#pragma unroll
                for (int msk = 1; msk < 16; msk <<= 1) {
                    s += __shfl_xor(s, msk, 64);
                    q += __shfl_xor(q, msk, 64);
                }
                if (n == 0) {
                    int cch = ot * 16 + quad * 4 + r;
                    lds_part[wq * 128 + cch * 2] = s;
                    lds_part[wq * 128 + cch * 2 + 1] = q;
                }
            }
        __syncthreads();
        if (tid < 128) {
            float s = lds_part[tid] + lds_part[128 + tid] + lds_part[256 + tid] + lds_part[384 + tid];
            atomicAdd(&STATS2[(qt & 3) * 256 + tid], s);
        }
    }
}

__device__ __forceinline__ void conv3_from_tile_cam(const unsigned short* tile,
        const unsigned short* __restrict__ WT, unsigned short* __restrict__ dst,
        int b, int l0, float* lds_part, float* __restrict__ STATS2,
        int blockx, int tl) {
    int w = tl >> 6, lane = tl & 63, n = lane & 15, quad = lane >> 4;
    int lrow = l0 + w * 16 + n;
    f32x4 acc[4];
#pragma unroll
    for (int ot = 0; ot < 4; ++ot) acc[ot] = (f32x4){0.f, 0.f, 0.f, 0.f};
#pragma unroll
    for (int t3 = 0; t3 < 3; ++t3) {
        int trow = w * 16 + n + t3;
        bshort8 fb0 = *(const bshort8*)(tile + trow * 72 + quad * 8);
        bshort8 fb1 = *(const bshort8*)(tile + trow * 72 + 32 + quad * 8);
#pragma unroll
        for (int ot = 0; ot < 4; ++ot) {
            bshort8 w0 = *(const bshort8*)(WT + ((size_t)(t3 * 64 + ot * 16 + n)) * IC + quad * 8);
            bshort8 w1 = *(const bshort8*)(WT + ((size_t)(t3 * 64 + ot * 16 + n)) * IC + 32 + quad * 8);
            acc[ot] = __builtin_amdgcn_mfma_f32_16x16x32_bf16(w0, fb0, acc[ot], 0, 0, 0);
            acc[ot] = __builtin_amdgcn_mfma_f32_16x16x32_bf16(w1, fb1, acc[ot], 0, 0, 0);
        }
    }
#pragma unroll
    for (int ot = 0; ot < 4; ++ot) {
        uint2 pv;
        pv.x = pk2(acc[ot][0], acc[ot][1]);
        pv.y = pk2(acc[ot][2], acc[ot][3]);
        *(uint2*)(dst + ((size_t)(b * LP + lrow)) * IC + ot * 16 + quad * 4) = pv;
    }
#pragma unroll
    for (int ot = 0; ot < 4; ++ot)
#pragma unroll
        for (int r = 0; r < 4; ++r) {
            float s = acc[ot][r], q = s * s;
#pragma unroll
            for (int msk = 1; msk < 16; msk <<= 1) {
                s += __shfl_xor(s, msk, 64);
                q += __shfl_xor(q, msk, 64);
            }
            if (n == 0) {
                int cch = ot * 16 + quad * 4 + r;
                lds_part[w * 128 + cch * 2] = s;
                lds_part[w * 128 + cch * 2 + 1] = q;
            }
        }
    __syncthreads();
    if (tl < 128) {
        float s = lds_part[tl] + lds_part[128 + tl] + lds_part[256 + tl] + lds_part[384 + tl];
        atomicAdd(&STATS2[(blockx & 3) * 256 + 128 + tl], s);
    }
}

__device__ void role_cam_full(char* sm, int tl, int lt, int b,
        const float* __restrict__ EPART, const unsigned short* __restrict__ Y2C,
        const float* __restrict__ STATS1,
        const float* __restrict__ g5c, const float* __restrict__ b5c,
        const float* __restrict__ gamma, const unsigned short* __restrict__ WT,
        unsigned short* __restrict__ Y52T, float* __restrict__ STATS2) {
    float* as = (float*)sm;                            // 4096 f32
    float* cA = as + 4096; float* cB = cA + 64;
    unsigned short* tile = (unsigned short*)(cB + 64); // [66][72]
    float* lds_part = (float*)(tile + 4752);           // 512 f32 (also fcol scratch)
    int l0 = lt * 64;
    load_coef(STATS1, g5c, b5c, 64, 64, cA, cB, tl);
    for (int idx = tl; idx < 4096; idx += 256) {       // sum gram partials (L2-resident)
        float s = 0.f;
#pragma unroll
        for (int ch = 0; ch < 16; ++ch) s += EPART[((size_t)(b * 16 + ch)) * 4096 + idx];
        as[idx] = s;
    }
    __syncthreads();
    {   // in-place softmax(min-shifted), 4 lanes per row
        int row = tl >> 2, qd = tl & 3;
        float v[16];
#pragma unroll
        for (int i = 0; i < 16; ++i) v[i] = as[row * 64 + qd * 16 + i];
        float mn = v[0];
#pragma unroll
        for (int i = 1; i < 16; ++i) mn = fminf(mn, v[i]);
        mn = fminf(mn, __shfl_xor(mn, 1, 64));
        mn = fminf(mn, __shfl_xor(mn, 2, 64));
        float s = 0.f;
#pragma unroll
        for (int i = 0; i < 16; ++i) { v[i] = __expf(mn - v[i]); s += v[i]; }
        s += __shfl_xor(s, 1, 64);
        s += __shfl_xor(s, 2, 64);
        float inv = 1.f / s;
#pragma unroll
        for (int i = 0; i < 16; ++i) as[row * 64 + qd * 16 + i] = v[i] * inv;
    }
    __syncthreads();
    float gm = gamma[0];
    {   // interior: lq row, cg = 16-channel group
        int lq = tl & 63, cg = tl >> 6;
        const unsigned short* fb = Y2C + (size_t)b * IC * LP + l0 + lq;
        float acc[16];
#pragma unroll
        for (int i = 0; i < 16; ++i) acc[i] = 0.f;
        for (int d4 = 0; d4 < 16; ++d4) {
            float fv[4];
#pragma unroll
            for (int i = 0; i < 4; ++i) {
                int d = 4 * d4 + i;
                fv[i] = fmaxf(fmaf(cA[d], bf2f(fb[(size_t)d * LP]), cB[d]), 0.f);
            }
#pragma unroll
            for (int cc = 0; cc < 16; ++cc) {
                const float4 a4 = *reinterpret_cast<const float4*>(as + (cg * 16 + cc) * 64 + d4 * 4);
                acc[cc] += a4.x * fv[0] + a4.y * fv[1] + a4.z * fv[2] + a4.w * fv[3];
            }
        }
#pragma unroll
        for (int cc = 0; cc < 16; ++cc) {
            int c = cg * 16 + cc;
            float res = fmaxf(fmaf(cA[c], bf2f(fb[(size_t)c * LP]), cB[c]), 0.f);
            tile[(1 + lq) * 72 + c] = f2bf(fmaf(gm, acc[cc], res));
        }
    }
    // halo: stage the two BN'd f-columns to LDS once
    float* fcol = lds_part;
    if (tl < 128) {
        int row = tl >> 6;
        int ch = tl & 63;
        int l = l0 - 1 + row * 65;
        float v = 0.f;
        if (l >= 0 && l < LP)
            v = fmaxf(fmaf(cA[ch], bf2f(Y2C[(size_t)b * IC * LP + (size_t)ch * LP + l]), cB[ch]), 0.f);
        fcol[row * 64 + ch] = v;
    }
    __syncthreads();
    if (tl < 128) {
        int sel = tl & 1;
        int row = sel ? 65 : 0;
        int ch = tl >> 1;
        int l = l0 - 1 + (sel ? 65 : 0);
        float val = 0.f;
        if (l >= 0 && l < LP) {
            const float* fc = fcol + sel * 64;
            float a = 0.f;
#pragma unroll 8
            for (int d = 0; d < 64; ++d) a = fmaf(as[ch * 64 + d], fc[d], a);
            val = fmaf(gm, a, fc[ch]);
        }
        tile[row * 72 + ch] = f2bf(val);
    }
    __syncthreads();
    conv3_from_tile_cam(tile, WT, Y52T, b, l0, lds_part, STATS2, lt, tl);
}

__global__ __launch_bounds__(256) void k_fuse2(
        const unsigned short* __restrict__ QT, const unsigned short* __restrict__ KT,
        const unsigned short* __restrict__ VB,
        const unsigned short* __restrict__ Y1T, const unsigned short* __restrict__ Y2C,
        const float* __restrict__ STATS1,
        const float* __restrict__ g5a, const float* __restrict__ b5a,
        const float* __restrict__ g5c, const float* __restrict__ b5c,
        const float* __restrict__ gpam, const float* __restrict__ gcam,
        const float* __restrict__ EPART, const unsigned short* __restrict__ WTall,
        unsigned short* __restrict__ Y51T, unsigned short* __restrict__ Y52T,
        float* __restrict__ STATS2) {
    extern __shared__ char dynsm[];
    int idx = blockIdx.x;
    if (idx < 272) {
        int b = idx / 34; int qt = idx - b * 34;
        role_pam_full(dynsm, qt, b, QT, KT, VB, Y1T, STATS1, g5a, b5a, gpam,
                      WTall, Y51T, STATS2);
    } else {
        int g = idx - 272;
        role_cam_full(dynsm, threadIdx.x, g & 31, g >> 5, EPART, Y2C, STATS1,
                      g5c, b5c, gcam, WTall + 12288, Y52T, STATS2);
    }
}

// ---- final conv1x1 pair + fused sasc projection (out pre-initialized to b8) ----
__global__ __launch_bounds__(256) void k_final(const unsigned short* __restrict__ Y51T,
        const unsigned short* __restrict__ Y52T, const float* __restrict__ STATS2,
        const float* __restrict__ g51, const float* __restrict__ b51,
        const float* __restrict__ g52, const float* __restrict__ b52,
        const unsigned short* __restrict__ W67,
        const float* __restrict__ b6, const float* __restrict__ b7,
        const float* __restrict__ W8,
        float* __restrict__ out_sa, float* __restrict__ out_sc,
        float* __restrict__ out_sasc) {
    __shared__ float cA[128], cB[128];
    __shared__ float fsw[4][64];
    __shared__ float chsum[64];
    int lt = blockIdx.x, og = blockIdx.y, b = blockIdx.z;
    int t = threadIdx.x;
    if (t < 128) {
        float s = STATS2[t * 2] + STATS2[256 + t * 2] + STATS2[512 + t * 2] + STATS2[768 + t * 2];
        float q = STATS2[t * 2 + 1] + STATS2[256 + t * 2 + 1] + STATS2[512 + t * 2 + 1] + STATS2[768 + t * 2 + 1];
        float mu = s * INVN, var = q * INVN - mu * mu;
        float gv = t < 64 ? g51[t] : g52[t - 64];
        float bv = t < 64 ? b51[t] : b52[t - 64];
        float A = gv * rsqrtf(var + BN_EPS);
        cA[t] = A; cB[t] = bv - mu * A;
    }
    __syncthreads();
    int w = t >> 6, lane = t & 63, n = lane & 15, quad = lane >> 4;
    int lrow = lt * 64 + w * 16 + n;
    float fs_lane[16];
    bshort8 ba[2], bb[2];
#pragma unroll
    for (int kt = 0; kt < 2; ++kt) {
        bshort8 ra = *(const bshort8*)(Y51T + ((size_t)(b * LP + lrow)) * IC + kt * 32 + quad * 8);
        bshort8 rb = *(const bshort8*)(Y52T + ((size_t)(b * LP + lrow)) * IC + kt * 32 + quad * 8);
        bshort8 fa, fb;
#pragma unroll
        for (int j = 0; j < 8; ++j) {
            int c = kt * 32 + quad * 8 + j;
            float v1 = fmaxf(fmaf(cA[c], bf2f((unsigned short)ra[j]), cB[c]), 0.f);
            float v2 = fmaxf(fmaf(cA[64 + c], bf2f((unsigned short)rb[j]), cB[64 + c]), 0.f);
            ((unsigned short*)&fa)[j] = f2bf(v1);
            ((unsigned short*)&fb)[j] = f2bf(v2);
            fs_lane[kt * 8 + j] = v1 + v2;
        }
        ba[kt] = fa; bb[kt] = fb;
    }
    f32x4 accA[4], accB[4];
#pragma unroll
    for (int ot = 0; ot < 4; ++ot) {
        accA[ot] = (f32x4){0.f, 0.f, 0.f, 0.f};
        accB[ot] = (f32x4){0.f, 0.f, 0.f, 0.f};
    }
#pragma unroll
    for (int ot = 0; ot < 4; ++ot)
#pragma unroll
        for (int kt = 0; kt < 2; ++kt) {
            bshort8 wa = *(const bshort8*)(W67 + (size_t)(og * 64 + ot * 16 + n) * IC + kt * 32 + quad * 8);
            bshort8 wb = *(const bshort8*)(W67 + 8192 + (size_t)(og * 64 + ot * 16 + n) * IC + kt * 32 + quad * 8);
            accA[ot] = __builtin_amdgcn_mfma_f32_16x16x32_bf16(wa, ba[kt], accA[ot], 0, 0, 0);
            accB[ot] = __builtin_amdgcn_mfma_f32_16x16x32_bf16(wb, bb[kt], accB[ot], 0, 0, 0);
        }
#pragma unroll
    for (int ot = 0; ot < 4; ++ot)
#pragma unroll
        for (int r = 0; r < 4; ++r) {
            int o = og * 64 + ot * 16 + quad * 4 + r;
            out_sa[((size_t)(b * OC + o)) * LP + lrow] = accA[ot][r] + b6[o];
            out_sc[((size_t)(b * OC + o)) * LP + lrow] = accB[ot][r] + b7[o];
        }
    if (og == 0) {
#pragma unroll
        for (int i = 0; i < 16; ++i) {
            float s = fs_lane[i];
#pragma unroll
            for (int msk = 1; msk < 16; msk <<= 1) s += __shfl_xor(s, msk, 64);
            if (n == 0) {
                int c = (i >> 3) * 32 + quad * 8 + (i & 7);
                fsw[w][c] = s;
            }
        }
        __syncthreads();
        if (t < 64) chsum[t] = fsw[0][t] + fsw[1][t] + fsw[2][t] + fsw[3][t];
        __syncthreads();
        if (t < 128) {
            float s = 0.f;
            for (int c = 0; c < 64; ++c) s = fmaf(W8[t * 64 + c], chsum[c], s);
            atomicAdd(&out_sasc[b * OC + t], s * (1.f / (float)LP));
        }
    }
}

extern "C" void kernel_launch(void* const* d_in, const int* in_sizes, int n_in,
                              void* d_out, int out_size, void* d_ws, size_t ws_size,
                              hipStream_t stream) {
    (void)in_sizes; (void)n_in; (void)out_size; (void)ws_size;
    const float* x    = (const float*)d_in[0];
    const float* W5a  = (const float*)d_in[1];
    const float* g5a  = (const float*)d_in[2];
    const float* b5a  = (const float*)d_in[3];
    const float* W5c  = (const float*)d_in[4];
    const float* g5c  = (const float*)d_in[5];
    const float* b5c  = (const float*)d_in[6];
    const float* Wq   = (const float*)d_in[7];
    const float* bq   = (const float*)d_in[8];
    const float* Wk   = (const float*)d_in[9];
    const float* bk   = (const float*)d_in[10];
    const float* Wv   = (const float*)d_in[11];
    const float* bv   = (const float*)d_in[12];
    const float* gpam = (const float*)d_in[13];
    const float* gcam = (const float*)d_in[14];
    const float* W51  = (const float*)d_in[15];
    const float* g51  = (const float*)d_in[16];
    const float* b51  = (const float*)d_in[17];
    const float* W52  = (const float*)d_in[18];
    const float* g52  = (const float*)d_in[19];
    const float* b52  = (const float*)d_in[20];
    const float* W6   = (const float*)d_in[21];
    const float* b6   = (const float*)d_in[22];
    const float* W7   = (const float*)d_in[23];
    const float* b7   = (const float*)d_in[24];
    const float* W8   = (const float*)d_in[25];
    const float* b8   = (const float*)d_in[26];

    float* ws = (float*)d_ws;
    float* out = (float*)d_out;
    unsigned short* Y1T  = (unsigned short*)(ws + OFF_Y1T);
    unsigned short* Y2C  = (unsigned short*)(ws + OFF_Y2C);
    unsigned short* Y51T = (unsigned short*)(ws + OFF_Y51T);
    unsigned short* Y52T = (unsigned short*)(ws + OFF_Y52T);
    unsigned short* VB   = (unsigned short*)(ws + OFF_VB);
    unsigned short* QT   = (unsigned short*)(ws + OFF_QT);
    unsigned short* KT   = (unsigned short*)(ws + OFF_KT);
    float* EPART  = ws + OFF_EPART;
    float* STATS1 = ws + OFF_STATS1;
    float* STATS2 = ws + OFF_STATS2;
    unsigned short* W5BF = (unsigned short*)(ws + OFF_W5BF);
    unsigned short* W67  = (unsigned short*)(ws + OFF_W67);
    unsigned short* WT   = (unsigned short*)(ws + OFF_WT);
    unsigned short* WQKV = (unsigned short*)(ws + OFF_WQKV);
    float* BQKV = ws + OFF_BQKV;

    float* out_sa = out + B * OC;
    float* out_sc = out + B * OC + (size_t)B * OC * LP;

    k_wprep<<<321, 256, 0, stream>>>(W5a, W5c, W6, W7, W51, W52, Wq, Wk, Wv,
                                     bq, bk, bv, b8, W5BF, W67, WT, WQKV, BQKV,
                                     STATS1, STATS2, out);
    k_conv1<<<dim3(32, B), 256, 0, stream>>>(x, W5BF, Y1T, Y2C, STATS1);
    k_fuse1<<<288, 256, 512, stream>>>(Y1T, Y2C, STATS1, g5a, b5a, g5c, b5c,
                                       WQKV, BQKV, QT, KT, VB, EPART);
    k_fuse2<<<528, 256, 46848, stream>>>(QT, KT, VB, Y1T, Y2C, STATS1,
                                         g5a, b5a, g5c, b5c, gpam, gcam,
                                         EPART, WT, Y51T, Y52T, STATS2);
    k_final<<<dim3(32, 2, B), 256, 0, stream>>>(Y51T, Y52T, STATS2, g51, b51, g52, b52,
                                                W67, b6, b7, W8, out_sa, out_sc, out);
}